// Round 6
// baseline (193.878 us; speedup 1.0000x reference)
//
#include <hip/hip_runtime.h>
#include <math.h>

// Problem constants (fixed by reference: enc (32,64,64,64) fp32, embed (512,64) fp32)
#define DQ 64
#define KQ 512
#define NVEC 131072
#define QOUT_SIZE (NVEC * DQ)              // 8388608
#define LOSS_OFF QOUT_SIZE
#define IDX_OFF (QOUT_SIZE + 1)

#define RPW 32                             // rows per wave (2 MFMA A-tiles)
#define WPB 16                             // waves per block (1024 threads)
#define VPB (RPW * WPB)                    // 512 rows per WG
#define NBLK (NVEC / VPB)                  // 256 blocks -> exactly 1 per CU
// Packed-key scheme: esq stored as |e|^2 + 256 so v = esq - 2*dot > 0 always
// (x_sq ~ chi2(64); 256 is 17 sigma -> impossible). Low 9 mantissa bits carry
// the code index (<=511 ulp ~ 0.002 at d2~60). TIE_THR = fp16-product 5.5
// sigma + pack noise (passed R14/R17 with identical absmax).
#define ESQ_OFF 256.0f
#define TIE_THR 0.09f

typedef __attribute__((ext_vector_type(8))) _Float16 half8;        // 8 f16 = 1 MFMA A/B frag
typedef __attribute__((ext_vector_type(4))) float f32x4;           // MFMA C/D frag

static __device__ __forceinline__ void cvt8h(float4 a, float4 b, half8& h) {
    // RNE f32->f16 (v_cvt_f16_f32 default mode).
    h[0] = (_Float16)a.x; h[1] = (_Float16)a.y; h[2] = (_Float16)a.z; h[3] = (_Float16)a.w;
    h[4] = (_Float16)b.x; h[5] = (_Float16)b.y; h[6] = (_Float16)b.z; h[7] = (_Float16)b.w;
}

// key = distance value with low 9 mantissa bits replaced by the code index.
// Values strictly positive -> IEEE float ordering == bit ordering.
static __device__ __forceinline__ float packk(float v, int code) {
    return __uint_as_float((__float_as_uint(v) & 0xFFFFFE00u) | (unsigned)code);
}

// R18. Post-mortem R0-R17: resident waves/CU == WPB in EVERY round (R0 4.3,
// R1 3.3, R2 7.9, R16 3.7, R17 4.0) -> the platform holds ~1 WG per CU
// regardless of LDS/VGPR/grid. So: (1) WPB=16 (1024 thr), 256 WGs = exactly
// 1/CU -> 16 resident waves/CU (4/SIMD) if the pattern holds, whole grid in
// one dispatch round. (2) INIT FUSED: embed->fp16 conversion + esq computed
// during staging (esq via shfl partner-sum, zero extra loads); loss zeroed by
// 4-byte hipMemsetAsync -> ONE kernel launch (every round paid ~51-71 us of
// 2-launch overhead). (3) TWO codebook copies in LDS (waves 0-7 / 8-15):
// LDS 137 KB pins provable residency at 1 WG/CU -> VGPR budget 512/4 = 128
// (R12 rule), demand ~100, no spill (R16's failure mode). (4) k-loop fully
// macro-unrolled w/ immediate offsets + X/Y ping-pong (R0 style; R2/R17's
// runtime-indexed loop drained lgkmcnt per iteration). fp16 single product:
// at 4 waves/SIMD the MFMA pipe alone is 4x128x19.4 cyc — hi/lo would triple.
// R3 lesson kept: VGPR arrays only indexed by fully-unrolled constants.
__global__ __launch_bounds__(1024) void vq_fused_kernel(const float* __restrict__ enc,
                                                        const float* __restrict__ embed,
                                                        float* __restrict__ out) {
    __shared__ unsigned short hs[2 * KQ * DQ]; // fp16 codebook x2 copies: 128 KB
    __shared__ float esq_s[KQ];                // 2 KB
    __shared__ int bidx_s[VPB];                // 2 KB
    __shared__ int flag_s[VPB];                // 2 KB
    __shared__ float red[WPB];

    const int tid = threadIdx.x;               // 0..1023
    const int lane = tid & 63;
    const int w = tid >> 6;                    // wave 0..15
    const int l15 = lane & 15;
    const int l4 = lane >> 4;                  // 0..3
    const int vb = blockIdx.x * VPB + w * RPW;

    // ---- Issue A loads FIRST (HBM latency overlaps staging). ----
    float4 raw[2][4];
#pragma unroll
    for (int a = 0; a < 2; a++) {
        const float* b_ = enc + (size_t)(vb + a * 16 + l15) * DQ + l4 * 8;
        raw[a][0] = ((const float4*)b_)[0];
        raw[a][1] = ((const float4*)b_)[1];
        raw[a][2] = ((const float4*)(b_ + 32))[0];
        raw[a][3] = ((const float4*)(b_ + 32))[1];
    }

    // ---- Fused init/staging: thread t converts embed values t*32..t*32+31.
    // row k = t>>1 (constant per thread), dims (t&1)*32 + j*8. Writes both
    // LDS copies in XOR-swizzled layout (chunk c at slot c^(k&7); proven
    // conflict-free for the k-loop reads in R14/R17). esq: partner-sum via
    // shfl_xor(ps,1) — zero extra global loads.
    {
        const int k = tid >> 1;
        const float* ep = embed + (size_t)tid * 32;
        float ps = 0.f;
#pragma unroll
        for (int j = 0; j < 4; j++) {
            float4 f0 = ((const float4*)ep)[2 * j];
            float4 f1 = ((const float4*)ep)[2 * j + 1];
            half8 h;
            cvt8h(f0, f1, h);
            const int c = (tid & 1) * 4 + j;           // 8-dim chunk index 0..7
            const int slot = c ^ (k & 7);              // XOR swizzle
            *(half8*)(hs + (size_t)k * DQ + slot * 8) = h;
            *(half8*)(hs + KQ * DQ + (size_t)k * DQ + slot * 8) = h;
            ps = fmaf(f0.x, f0.x, ps); ps = fmaf(f0.y, f0.y, ps);
            ps = fmaf(f0.z, f0.z, ps); ps = fmaf(f0.w, f0.w, ps);
            ps = fmaf(f1.x, f1.x, ps); ps = fmaf(f1.y, f1.y, ps);
            ps = fmaf(f1.z, f1.z, ps); ps = fmaf(f1.w, f1.w, ps);
        }
        const float pst = ps + __shfl_xor(ps, 1);      // partner t^1 is same wave
        if (!(tid & 1)) esq_s[k] = pst + ESQ_OFF;
    }
    __syncthreads();                           // the ONLY block-wide barrier before end

    // Convert this wave's A rows to fp16 fragments.
    half8 ahA[2], ahB[2];
#pragma unroll
    for (int a = 0; a < 2; a++) {
        cvt8h(raw[a][0], raw[a][1], ahA[a]);
        cvt8h(raw[a][2], raw[a][3], ahB[a]);
    }

    float m1[8], m2[8];
#pragma unroll
    for (int r = 0; r < 8; r++) { m1[r] = 3.0e38f; m2[r] = 3.0e38f; }

    // Swizzled B-frag slot offsets (elements); key = l15&7 (batch*16 == 0 mod 8).
    const int sl0 = (l4 ^ (l15 & 7)) * 8;      // chunk l4     (dims l4*8..+8)
    const int sl1 = sl0 ^ 32;                  // chunk 4+l4   (dims 32+l4*8..+8)
    // Waves 0-7 read copy 0; waves 8-15 read copy 1.
    const unsigned short* hrow = hs + (w >> 3) * (KQ * DQ) + l15 * DQ;

    // k-loop: 16 pairs of 16-code batches, fully unrolled with immediate
    // offsets, X/Y ping-pong (load next pair's frags under current MFMA+VALU).
#define LDP(B0, B1, B2, B3, E0, E1, P) { \
    B0 = *(const half8*)(hrow + (2 * (P)) * 1024 + sl0); \
    B1 = *(const half8*)(hrow + (2 * (P)) * 1024 + sl1); \
    B2 = *(const half8*)(hrow + (2 * (P) + 1) * 1024 + sl0); \
    B3 = *(const half8*)(hrow + (2 * (P) + 1) * 1024 + sl1); \
    E0 = esq_s[(2 * (P)) * 16 + l15]; \
    E1 = esq_s[(2 * (P) + 1) * 16 + l15]; }

#define BODY(P, B0, B1, B2, B3, E0, E1) { \
    const int c0 = (2 * (P)) * 16 + l15; \
    _Pragma("unroll") \
    for (int a = 0; a < 2; a++) { \
        f32x4 acc0 = {0.f, 0.f, 0.f, 0.f}; \
        f32x4 acc1 = {0.f, 0.f, 0.f, 0.f}; \
        acc0 = __builtin_amdgcn_mfma_f32_16x16x32_f16(ahA[a], B0, acc0, 0, 0, 0); \
        acc0 = __builtin_amdgcn_mfma_f32_16x16x32_f16(ahB[a], B1, acc0, 0, 0, 0); \
        acc1 = __builtin_amdgcn_mfma_f32_16x16x32_f16(ahA[a], B2, acc1, 0, 0, 0); \
        acc1 = __builtin_amdgcn_mfma_f32_16x16x32_f16(ahB[a], B3, acc1, 0, 0, 0); \
        _Pragma("unroll") \
        for (int r = 0; r < 4; r++) { \
            const int i = a * 4 + r; \
            const float k0 = packk(fmaf(-2.0f, acc0[r], E0), c0); \
            const float k1 = packk(fmaf(-2.0f, acc1[r], E1), c0 + 16); \
            const float mo = m1[i]; \
            m1[i] = fminf(fminf(mo, k0), k1);                          /* v_min3 */ \
            m2[i] = fminf(m2[i], __builtin_amdgcn_fmed3f(mo, k0, k1)); /* 2nd-best */ \
        } \
    } }

    {
        half8 X0, X1, X2, X3, Y0, Y1, Y2, Y3;
        float xe0, xe1, ye0, ye1;
        LDP(X0, X1, X2, X3, xe0, xe1, 0)
        LDP(Y0, Y1, Y2, Y3, ye0, ye1, 1)  BODY(0,  X0, X1, X2, X3, xe0, xe1)
        LDP(X0, X1, X2, X3, xe0, xe1, 2)  BODY(1,  Y0, Y1, Y2, Y3, ye0, ye1)
        LDP(Y0, Y1, Y2, Y3, ye0, ye1, 3)  BODY(2,  X0, X1, X2, X3, xe0, xe1)
        LDP(X0, X1, X2, X3, xe0, xe1, 4)  BODY(3,  Y0, Y1, Y2, Y3, ye0, ye1)
        LDP(Y0, Y1, Y2, Y3, ye0, ye1, 5)  BODY(4,  X0, X1, X2, X3, xe0, xe1)
        LDP(X0, X1, X2, X3, xe0, xe1, 6)  BODY(5,  Y0, Y1, Y2, Y3, ye0, ye1)
        LDP(Y0, Y1, Y2, Y3, ye0, ye1, 7)  BODY(6,  X0, X1, X2, X3, xe0, xe1)
        LDP(X0, X1, X2, X3, xe0, xe1, 8)  BODY(7,  Y0, Y1, Y2, Y3, ye0, ye1)
        LDP(Y0, Y1, Y2, Y3, ye0, ye1, 9)  BODY(8,  X0, X1, X2, X3, xe0, xe1)
        LDP(X0, X1, X2, X3, xe0, xe1, 10) BODY(9,  Y0, Y1, Y2, Y3, ye0, ye1)
        LDP(Y0, Y1, Y2, Y3, ye0, ye1, 11) BODY(10, X0, X1, X2, X3, xe0, xe1)
        LDP(X0, X1, X2, X3, xe0, xe1, 12) BODY(11, Y0, Y1, Y2, Y3, ye0, ye1)
        LDP(Y0, Y1, Y2, Y3, ye0, ye1, 13) BODY(12, X0, X1, X2, X3, xe0, xe1)
        LDP(X0, X1, X2, X3, xe0, xe1, 14) BODY(13, Y0, Y1, Y2, Y3, ye0, ye1)
        LDP(Y0, Y1, Y2, Y3, ye0, ye1, 15) BODY(14, X0, X1, X2, X3, xe0, xe1)
        BODY(15, Y0, Y1, Y2, Y3, ye0, ye1)
    }
#undef LDP
#undef BODY

    // Cross-lane merge over the 16 cols (xor on lane&15 bits). Keys carry the
    // code index -> only 2 shuffles per r.
#pragma unroll
    for (int m = 1; m <= 8; m <<= 1) {
#pragma unroll
        for (int r = 0; r < 8; r++) {
            const float o1 = __shfl_xor(m1[r], m);
            const float o2 = __shfl_xor(m2[r], m);
            m2[r] = fminf(fminf(m2[r], o2), fmaxf(m1[r], o1));
            m1[r] = fminf(m1[r], o1);
        }
    }

    if (l15 == 0) {
#pragma unroll
        for (int a = 0; a < 2; a++)
#pragma unroll
            for (int r = 0; r < 4; r++) {
                const int row = a * 16 + l4 * 4 + r;
                bidx_s[w * RPW + row] = (int)(__float_as_uint(m1[a * 4 + r]) & 511u);
                flag_s[w * RPW + row] = (m2[a * 4 + r] - m1[a * 4 + r] < TIE_THR) ? 1 : 0;
            }
    }
    // bidx_s/flag_s are per-wave segments -> wave-internal visibility only.

    // Exact fp64 rescan of flagged rows (wave-uniform branch; ~1.5% of rows).
    for (int row = 0; row < RPW; row++) {
        if (flag_s[w * RPW + row]) {
            const int v = vb + row;
            const float4* xe = (const float4*)(enc + (size_t)v * DQ);
            unsigned long long best = ~0ULL;
            for (int q = 0; q < 8; q++) {
                const int c = lane * 8 + q;
                const float4* ee = (const float4*)(embed + (size_t)c * DQ);
                double a = 0.0;
                for (int j = 0; j < 16; j++) {          // global ptrs: runtime j fine
                    float4 xx = xe[j], ez = ee[j];
                    double d0 = (double)xx.x - (double)ez.x; a = fma(d0, d0, a);
                    double d1 = (double)xx.y - (double)ez.y; a = fma(d1, d1, a);
                    double d2 = (double)xx.z - (double)ez.z; a = fma(d2, d2, a);
                    double d3 = (double)xx.w - (double)ez.w; a = fma(d3, d3, a);
                }
                unsigned long long pk =
                    (((unsigned long long)__double_as_longlong(a)) & ~511ULL) | (unsigned)c;
                best = (pk < best) ? pk : best;
            }
#pragma unroll
            for (int mm = 1; mm < 64; mm <<= 1) {
                unsigned long long ob = (unsigned long long)__shfl_xor((long long)best, mm);
                best = (ob < best) ? ob : best;
            }
            if (lane == 0) bidx_s[w * RPW + row] = (int)(best & 511ULL);
        }
    }

    // Epilogue: per tile a, lane handles row a*16+l15, chunks l4*8 and
    // 32+l4*8. x recomputed from the fp16 frags (2^-11 rel err; loss-only).
    float lsum = 0.f;
#pragma unroll
    for (int a = 0; a < 2; a++) {
        const int myv = vb + a * 16 + l15;
        const int qb = bidx_s[w * RPW + a * 16 + l15];
        const float* qbase = embed + (size_t)qb * DQ + l4 * 8;
        const float4* qa = (const float4*)qbase;
        const float4* qc = (const float4*)(qbase + 32);
        float4 q0 = qa[0], q1 = qa[1], q2 = qc[0], q3 = qc[1];
        float* obase = out + (size_t)myv * DQ + l4 * 8;
        ((float4*)obase)[0] = q0; ((float4*)obase)[1] = q1;
        ((float4*)(obase + 32))[0] = q2; ((float4*)(obase + 32))[1] = q3;
        if (l4 == 0) out[IDX_OFF + myv] = (float)qb;

        float d;
        d = q0.x - (float)ahA[a][0]; lsum = fmaf(d, d, lsum);
        d = q0.y - (float)ahA[a][1]; lsum = fmaf(d, d, lsum);
        d = q0.z - (float)ahA[a][2]; lsum = fmaf(d, d, lsum);
        d = q0.w - (float)ahA[a][3]; lsum = fmaf(d, d, lsum);
        d = q1.x - (float)ahA[a][4]; lsum = fmaf(d, d, lsum);
        d = q1.y - (float)ahA[a][5]; lsum = fmaf(d, d, lsum);
        d = q1.z - (float)ahA[a][6]; lsum = fmaf(d, d, lsum);
        d = q1.w - (float)ahA[a][7]; lsum = fmaf(d, d, lsum);
        d = q2.x - (float)ahB[a][0]; lsum = fmaf(d, d, lsum);
        d = q2.y - (float)ahB[a][1]; lsum = fmaf(d, d, lsum);
        d = q2.z - (float)ahB[a][2]; lsum = fmaf(d, d, lsum);
        d = q2.w - (float)ahB[a][3]; lsum = fmaf(d, d, lsum);
        d = q3.x - (float)ahB[a][4]; lsum = fmaf(d, d, lsum);
        d = q3.y - (float)ahB[a][5]; lsum = fmaf(d, d, lsum);
        d = q3.z - (float)ahB[a][6]; lsum = fmaf(d, d, lsum);
        d = q3.w - (float)ahB[a][7]; lsum = fmaf(d, d, lsum);
    }

#pragma unroll
    for (int off = 32; off > 0; off >>= 1) lsum += __shfl_down(lsum, off);
    if (lane == 0) red[w] = lsum;
    __syncthreads();
    if (tid == 0) {
        float s = 0.f;
#pragma unroll
        for (int i = 0; i < WPB; i++) s += red[i];
        atomicAdd(out + LOSS_OFF, s * (2.0f / (float)QOUT_SIZE));
    }
}

extern "C" void kernel_launch(void* const* d_in, const int* in_sizes, int n_in,
                              void* d_out, int out_size, void* d_ws, size_t ws_size,
                              hipStream_t stream) {
    const float* enc = (const float*)d_in[0];
    const float* embed = (const float*)d_in[1];
    float* out = (float*)d_out;

    // Zero the loss accumulator (4 bytes) — graph-capture-safe async memset;
    // replaces the entire former init kernel (codebook conversion is fused).
    hipMemsetAsync((void*)(out + LOSS_OFF), 0, sizeof(float), stream);
    hipLaunchKernelGGL(vq_fused_kernel, dim3(NBLK), dim3(1024), 0, stream,
                       enc, embed, out);
}

// Round 7
// 185.114 us; speedup vs baseline: 1.0473x; 1.0473x over previous
//
#include <hip/hip_runtime.h>
#include <math.h>

// Problem constants (fixed by reference: enc (32,64,64,64) fp32, embed (512,64) fp32)
#define DQ 64
#define KQ 512
#define NVEC 131072
#define QOUT_SIZE (NVEC * DQ)              // 8388608
#define LOSS_OFF QOUT_SIZE
#define IDX_OFF (QOUT_SIZE + 1)

#define RPW 32                             // rows per wave (2 MFMA A-tiles)
#define WPB 4                              // waves per block (256 threads) — R0's shape
#define VPB (RPW * WPB)                    // 128 rows per block
#define NBLK (NVEC / VPB)                  // 1024 blocks — R0's shape
#define SC 128                             // codes per LDS stage (2x R0: fp16 halves bytes,
                                           // SC=128 restores R0's ~36 KB LDS footprint ->
                                           // provable 4 WGs/CU -> VGPR budget 128, like R0)
#define NST (KQ / SC)                      // 4 stages
#define SDQ (SC * DQ)                      // 8192 halfs per stage buffer (16 KB)
// Packed-key scheme: esq stored as |e|^2 + 256 so v = esq - 2*dot > 0 always
// (x_sq ~ chi2(64); 256 is 17 sigma -> impossible). Low 9 mantissa bits carry
// the code index (<=511 ulp ~ 0.002 at d2~60). TIE_THR = fp16-product 5.5
// sigma + pack noise. Validated R14/R17/R18: absmax 0.0001220703 (== R0's).
#define ESQ_OFF 256.0f
#define TIE_THR 0.09f

typedef __attribute__((ext_vector_type(8))) _Float16 half8;        // 8 f16 = 1 MFMA A/B frag
typedef __attribute__((ext_vector_type(4))) float f32x4;           // MFMA C/D frag

static __device__ __forceinline__ void cvt8h(float4 a, float4 b, half8& h) {
    // RNE f32->f16 (v_cvt_f16_f32 default mode).
    h[0] = (_Float16)a.x; h[1] = (_Float16)a.y; h[2] = (_Float16)a.z; h[3] = (_Float16)a.w;
    h[4] = (_Float16)b.x; h[5] = (_Float16)b.y; h[6] = (_Float16)b.z; h[7] = (_Float16)b.w;
}

// key = distance value with low 9 mantissa bits replaced by the code index.
// Values strictly positive -> IEEE float ordering == bit ordering.
static __device__ __forceinline__ float packk(float v, int code) {
    return __uint_as_float((__float_as_uint(v) & 0xFFFFFE00u) | (unsigned)code);
}

// Init: fp16 codebook in XOR-SWIZZLED layout (chunk c of row k stored at slot
// c ^ (k&7)) so main-kernel ds_read_b128 B-frag reads are conflict-free while
// staging stays a verbatim contiguous copy (conflicts == 0 in R0/R14/R17).
// esq = |e|^2 + 256 (see above).
__global__ void vq_init_kernel(const float* __restrict__ embed,
                               unsigned short* __restrict__ eh,
                               float* __restrict__ esq,
                               float* __restrict__ out) {
    const int t = blockIdx.x * 64 + threadIdx.x;   // 0..4095
    if (t == 0) out[LOSS_OFF] = 0.0f;
    const int k = t >> 3;            // codebook row
    const int c = t & 7;             // 16-byte chunk (8 dims)
    const float4* p = (const float4*)(embed + (size_t)k * DQ + c * 8);
    float4 a = p[0], b = p[1];
    half8 h;
    cvt8h(a, b, h);
    const int slot = c ^ (k & 7);    // XOR swizzle
    *(half8*)(eh + (size_t)k * DQ + slot * 8) = h;

    float ps = 0.f;
    ps = fmaf(a.x, a.x, ps); ps = fmaf(a.y, a.y, ps); ps = fmaf(a.z, a.z, ps); ps = fmaf(a.w, a.w, ps);
    ps = fmaf(b.x, b.x, ps); ps = fmaf(b.y, b.y, ps); ps = fmaf(b.z, b.z, ps); ps = fmaf(b.w, b.w, ps);
    ps += __shfl_xor(ps, 1);
    ps += __shfl_xor(ps, 2);
    ps += __shfl_xor(ps, 4);
    if (c == 0) esq[k] = ps + ESQ_OFF;
}

// R19. Scoreboard after 6 rounds: R0 (bf16 hi/lo, 4-wave WGs, 1024 blocks,
// staged-LDS pipeline, barrier/stage) = 76.7 us is STILL the best; every
// restructure (R1 100, R2 111, R16 153, R17 113, R18 124) lost. R18 also
// proved: (a) at 1024 thr the allocator sizes VGPRs by THREAD-SLOT occupancy
// (2048/1024=2 WGs -> 64 regs) ignoring LDS -> spills (+17 MB scratch
// traffic); (b) the ~65-70 us bench-vs-kernel gap is iteration-fixed, not
// per-launch (1-launch fusion changed nothing). This round: ONE validated
// change transplanted into R0's winning structure — fp16 single-product
// (3x less MFMA, proven R1 via MfmaUtil*dur; absmax identical) + pack-key
// min3/med3 bookkeeping (0.6x VALU, validated R14/R17/R18). SC=128 keeps
// LDS at ~35.5 KB == R0's footprint -> same allocator outcome (4 WGs
// provable, 128-reg budget, no spill). 4 stages instead of 8: half the
// barriers, half the staged bytes. Every per-wave cost <= R0's.
// R3 lesson kept: VGPR arrays only indexed by fully-unrolled constants.
__global__ __launch_bounds__(256) void vq_mfma_kernel(const float* __restrict__ enc,
                                                      const float* __restrict__ embed,
                                                      const unsigned short* __restrict__ eh,
                                                      const float* __restrict__ esq,
                                                      float* __restrict__ out) {
    __shared__ unsigned short hs[2 * SDQ];     // fp16 stages (dbuf): 32 KB
    __shared__ float esq_s[KQ];                // 2 KB
    __shared__ int bidx_s[VPB];                // 0.5 KB
    __shared__ int flag_s[VPB];                // 0.5 KB
    __shared__ float red[WPB];

    const int tid = threadIdx.x;               // 0..255
    const int lane = tid & 63;
    const int w = tid >> 6;                    // wave 0..3
    const int l15 = lane & 15;
    const int l4 = lane >> 4;                  // 0..3
    const int vb = blockIdx.x * VPB + w * RPW;

    // ---- Issue A loads FIRST (HBM latency overlaps staging). ----
    float4 raw[2][4];
#pragma unroll
    for (int a = 0; a < 2; a++) {
        const float* b_ = enc + (size_t)(vb + a * 16 + l15) * DQ + l4 * 8;
        raw[a][0] = ((const float4*)b_)[0];
        raw[a][1] = ((const float4*)b_)[1];
        raw[a][2] = ((const float4*)(b_ + 32))[0];
        raw[a][3] = ((const float4*)(b_ + 32))[1];
    }

    // ---- Staging prologue (R0 scheme): thread stages 64 B per stage. ----
    half8 r0 = *(const half8*)(eh + tid * 8);
    half8 r1 = *(const half8*)(eh + 2048 + tid * 8);
    half8 r2 = *(const half8*)(eh + 4096 + tid * 8);
    half8 r3 = *(const half8*)(eh + 6144 + tid * 8);
    // write stage 0 into buf 0
    *(half8*)(hs + tid * 8) = r0;        *(half8*)(hs + 2048 + tid * 8) = r1;
    *(half8*)(hs + 4096 + tid * 8) = r2; *(half8*)(hs + 6144 + tid * 8) = r3;
    // prefetch stage 1 into regs
    r0 = *(const half8*)(eh + SDQ + tid * 8);
    r1 = *(const half8*)(eh + SDQ + 2048 + tid * 8);
    r2 = *(const half8*)(eh + SDQ + 4096 + tid * 8);
    r3 = *(const half8*)(eh + SDQ + 6144 + tid * 8);

    esq_s[tid] = esq[tid];
    esq_s[tid + 256] = esq[tid + 256];

    // Convert this wave's A rows to fp16 fragments.
    half8 ahA[2], ahB[2];
#pragma unroll
    for (int a = 0; a < 2; a++) {
        cvt8h(raw[a][0], raw[a][1], ahA[a]);
        cvt8h(raw[a][2], raw[a][3], ahB[a]);
    }

    float m1[8], m2[8];
#pragma unroll
    for (int r = 0; r < 8; r++) { m1[r] = 3.0e38f; m2[r] = 3.0e38f; }

    // Swizzled B-frag slot offsets (elements); key = l15&7 (batch*16 == 0 mod 8).
    const int sl0 = (l4 ^ (l15 & 7)) * 8;      // chunk l4     (dims l4*8..+8)
    const int sl1 = sl0 ^ 32;                  // chunk 4+l4   (dims 32+l4*8..+8)

#define LDP(B0, B1, B2, B3, E0, E1, ST, P) { \
    B0 = *(const half8*)(hrow + (2 * (P)) * 1024 + sl0); \
    B1 = *(const half8*)(hrow + (2 * (P)) * 1024 + sl1); \
    B2 = *(const half8*)(hrow + (2 * (P) + 1) * 1024 + sl0); \
    B3 = *(const half8*)(hrow + (2 * (P) + 1) * 1024 + sl1); \
    E0 = esq_s[(ST) * SC + (2 * (P)) * 16 + l15]; \
    E1 = esq_s[(ST) * SC + (2 * (P) + 1) * 16 + l15]; }

#define BODY(ST, P, B0, B1, B2, B3, E0, E1) { \
    const int c0 = (ST) * SC + (2 * (P)) * 16 + l15; \
    _Pragma("unroll") \
    for (int a = 0; a < 2; a++) { \
        f32x4 acc0 = {0.f, 0.f, 0.f, 0.f}; \
        f32x4 acc1 = {0.f, 0.f, 0.f, 0.f}; \
        acc0 = __builtin_amdgcn_mfma_f32_16x16x32_f16(ahA[a], B0, acc0, 0, 0, 0); \
        acc0 = __builtin_amdgcn_mfma_f32_16x16x32_f16(ahB[a], B1, acc0, 0, 0, 0); \
        acc1 = __builtin_amdgcn_mfma_f32_16x16x32_f16(ahA[a], B2, acc1, 0, 0, 0); \
        acc1 = __builtin_amdgcn_mfma_f32_16x16x32_f16(ahB[a], B3, acc1, 0, 0, 0); \
        _Pragma("unroll") \
        for (int r = 0; r < 4; r++) { \
            const int i = a * 4 + r; \
            const float k0 = packk(fmaf(-2.0f, acc0[r], E0), c0); \
            const float k1 = packk(fmaf(-2.0f, acc1[r], E1), c0 + 16); \
            const float mo = m1[i]; \
            m1[i] = fminf(fminf(mo, k0), k1);                          /* v_min3 */ \
            m2[i] = fminf(m2[i], __builtin_amdgcn_fmed3f(mo, k0, k1)); /* 2nd-best */ \
        } \
    } }

    // ---- 4-stage pipeline (R0 scheme): barrier / write-next / prefetch+2 /
    // compute. Within a stage: 4 batch-pairs, X/Y ping-pong, immediate offsets.
    for (int st = 0; st < NST; st++) {
        // Drains: LDS writes of buf[st&1] (done last iter) + global loads
        // issued last iter (they had a full stage of compute cover).
        __syncthreads();
        if (st < NST - 1) {                  // write stage st+1 into other buf
            unsigned short* hw = hs + ((st + 1) & 1) * SDQ;
            *(half8*)(hw + tid * 8) = r0;        *(half8*)(hw + 2048 + tid * 8) = r1;
            *(half8*)(hw + 4096 + tid * 8) = r2; *(half8*)(hw + 6144 + tid * 8) = r3;
        }
        if (st < NST - 2) {                  // prefetch stage st+2 (overlaps compute)
            const int o = (st + 2) * SDQ;
            r0 = *(const half8*)(eh + o + tid * 8);
            r1 = *(const half8*)(eh + o + 2048 + tid * 8);
            r2 = *(const half8*)(eh + o + 4096 + tid * 8);
            r3 = *(const half8*)(eh + o + 6144 + tid * 8);
        }
        const unsigned short* hb = hs + (st & 1) * SDQ;
        const unsigned short* hrow = hb + l15 * DQ;    // batch b adds b*1024 elems

        half8 X0, X1, X2, X3, Y0, Y1, Y2, Y3;
        float xe0, xe1, ye0, ye1;
        LDP(X0, X1, X2, X3, xe0, xe1, st, 0)
        LDP(Y0, Y1, Y2, Y3, ye0, ye1, st, 1)
        BODY(st, 0, X0, X1, X2, X3, xe0, xe1)
        LDP(X0, X1, X2, X3, xe0, xe1, st, 2)
        BODY(st, 1, Y0, Y1, Y2, Y3, ye0, ye1)
        LDP(Y0, Y1, Y2, Y3, ye0, ye1, st, 3)
        BODY(st, 2, X0, X1, X2, X3, xe0, xe1)
        BODY(st, 3, Y0, Y1, Y2, Y3, ye0, ye1)
    }
#undef LDP
#undef BODY

    // Cross-lane merge over the 16 cols (xor on lane&15 bits). Keys carry the
    // code index -> only 2 shuffles per r.
#pragma unroll
    for (int m = 1; m <= 8; m <<= 1) {
#pragma unroll
        for (int r = 0; r < 8; r++) {
            const float o1 = __shfl_xor(m1[r], m);
            const float o2 = __shfl_xor(m2[r], m);
            m2[r] = fminf(fminf(m2[r], o2), fmaxf(m1[r], o1));
            m1[r] = fminf(m1[r], o1);
        }
    }

    if (l15 == 0) {
#pragma unroll
        for (int a = 0; a < 2; a++)
#pragma unroll
            for (int r = 0; r < 4; r++) {
                const int row = a * 16 + l4 * 4 + r;
                bidx_s[w * RPW + row] = (int)(__float_as_uint(m1[a * 4 + r]) & 511u);
                flag_s[w * RPW + row] = (m2[a * 4 + r] - m1[a * 4 + r] < TIE_THR) ? 1 : 0;
            }
    }
    // bidx_s/flag_s are per-wave segments -> wave-internal visibility only.

    // Exact fp64 rescan of flagged rows (wave-uniform branch; ~1.5% of rows).
    for (int row = 0; row < RPW; row++) {
        if (flag_s[w * RPW + row]) {
            const int v = vb + row;
            const float4* xe = (const float4*)(enc + (size_t)v * DQ);
            unsigned long long best = ~0ULL;
            for (int q = 0; q < 8; q++) {
                const int c = lane * 8 + q;
                const float4* ee = (const float4*)(embed + (size_t)c * DQ);
                double a = 0.0;
                for (int j = 0; j < 16; j++) {          // global ptrs: runtime j fine
                    float4 xx = xe[j], ez = ee[j];
                    double d0 = (double)xx.x - (double)ez.x; a = fma(d0, d0, a);
                    double d1 = (double)xx.y - (double)ez.y; a = fma(d1, d1, a);
                    double d2 = (double)xx.z - (double)ez.z; a = fma(d2, d2, a);
                    double d3 = (double)xx.w - (double)ez.w; a = fma(d3, d3, a);
                }
                unsigned long long pk =
                    (((unsigned long long)__double_as_longlong(a)) & ~511ULL) | (unsigned)c;
                best = (pk < best) ? pk : best;
            }
#pragma unroll
            for (int mm = 1; mm < 64; mm <<= 1) {
                unsigned long long ob = (unsigned long long)__shfl_xor((long long)best, mm);
                best = (ob < best) ? ob : best;
            }
            if (lane == 0) bidx_s[w * RPW + row] = (int)(best & 511ULL);
        }
    }

    // Epilogue: per tile a, lane handles row a*16+l15, chunks l4*8 and
    // 32+l4*8. x recomputed from the fp16 frags (2^-11 rel err; loss-only).
    float lsum = 0.f;
#pragma unroll
    for (int a = 0; a < 2; a++) {
        const int myv = vb + a * 16 + l15;
        const int qb = bidx_s[w * RPW + a * 16 + l15];
        const float* qbase = embed + (size_t)qb * DQ + l4 * 8;
        const float4* qa = (const float4*)qbase;
        const float4* qc = (const float4*)(qbase + 32);
        float4 q0 = qa[0], q1 = qa[1], q2 = qc[0], q3 = qc[1];
        float* obase = out + (size_t)myv * DQ + l4 * 8;
        ((float4*)obase)[0] = q0; ((float4*)obase)[1] = q1;
        ((float4*)(obase + 32))[0] = q2; ((float4*)(obase + 32))[1] = q3;
        if (l4 == 0) out[IDX_OFF + myv] = (float)qb;

        float d;
        d = q0.x - (float)ahA[a][0]; lsum = fmaf(d, d, lsum);
        d = q0.y - (float)ahA[a][1]; lsum = fmaf(d, d, lsum);
        d = q0.z - (float)ahA[a][2]; lsum = fmaf(d, d, lsum);
        d = q0.w - (float)ahA[a][3]; lsum = fmaf(d, d, lsum);
        d = q1.x - (float)ahA[a][4]; lsum = fmaf(d, d, lsum);
        d = q1.y - (float)ahA[a][5]; lsum = fmaf(d, d, lsum);
        d = q1.z - (float)ahA[a][6]; lsum = fmaf(d, d, lsum);
        d = q1.w - (float)ahA[a][7]; lsum = fmaf(d, d, lsum);
        d = q2.x - (float)ahB[a][0]; lsum = fmaf(d, d, lsum);
        d = q2.y - (float)ahB[a][1]; lsum = fmaf(d, d, lsum);
        d = q2.z - (float)ahB[a][2]; lsum = fmaf(d, d, lsum);
        d = q2.w - (float)ahB[a][3]; lsum = fmaf(d, d, lsum);
        d = q3.x - (float)ahB[a][4]; lsum = fmaf(d, d, lsum);
        d = q3.y - (float)ahB[a][5]; lsum = fmaf(d, d, lsum);
        d = q3.z - (float)ahB[a][6]; lsum = fmaf(d, d, lsum);
        d = q3.w - (float)ahB[a][7]; lsum = fmaf(d, d, lsum);
    }

#pragma unroll
    for (int off = 32; off > 0; off >>= 1) lsum += __shfl_down(lsum, off);
    if (lane == 0) red[w] = lsum;
    __syncthreads();
    if (tid == 0) {
        float s = (red[0] + red[1]) + (red[2] + red[3]);
        atomicAdd(out + LOSS_OFF, s * (2.0f / (float)QOUT_SIZE));
    }
}

extern "C" void kernel_launch(void* const* d_in, const int* in_sizes, int n_in,
                              void* d_out, int out_size, void* d_ws, size_t ws_size,
                              hipStream_t stream) {
    const float* enc = (const float*)d_in[0];
    const float* embed = (const float*)d_in[1];
    float* out = (float*)d_out;
    // ws layout: eh[512*64] u16 | esq[512] f32  (~66 KB)
    unsigned short* eh = (unsigned short*)d_ws;
    float* esq = (float*)(eh + KQ * DQ);

    hipLaunchKernelGGL(vq_init_kernel, dim3(64), dim3(64), 0, stream,
                       embed, eh, esq, out);
    hipLaunchKernelGGL(vq_mfma_kernel, dim3(NBLK), dim3(256), 0, stream,
                       enc, embed, eh, esq, out);
}